// Round 1
// baseline (9155.339 us; speedup 1.0000x reference)
//
#include <hip/hip_runtime.h>
#include <hip/hip_bf16.h>

typedef __attribute__((ext_vector_type(8))) short bf16x8;
typedef __attribute__((ext_vector_type(4))) float f32x4;
typedef unsigned int u32;
typedef unsigned long long u64;

static constexpr int TT = 1024, BB = 256, HH = 256, FF = 73, OO = 35;
static constexpr int NB = 8;    // batch tiles
static constexpr int NJ = 8;    // gate-slice blocks per tile
static constexpr int BT = 32;   // batch rows per tile
static constexpr int HS = 32;   // hidden cols per slice
static constexpr int DSLOT = 8; // ring depth
static constexpr int LDSK = 520; // padded A row (bf16 elems; K max 512; +8 pad -> 2-way banks only)
static constexpr int HFIN_OFF = BB * OO;              // 8960
static constexpr int CFIN_OFF = HFIN_OFF + 3 * BB * HH; // + 196608

union FragU { uint4 u; bf16x8 b; };

__device__ __forceinline__ unsigned short f2bf(float f) {
  __hip_bfloat16 h = __float2bfloat16(f);
  union { __hip_bfloat16 h; unsigned short s; } cv; cv.h = h; return cv.s;
}
__device__ __forceinline__ u64 pack4bf(float a, float b, float c, float d) {
  return (u64)f2bf(a) | ((u64)f2bf(b) << 16) | ((u64)f2bf(c) << 32) | ((u64)f2bf(d) << 48);
}
__device__ __forceinline__ float fsig(float x) { return 1.f / (1.f + __expf(-x)); }
__device__ __forceinline__ float ftanh(float x) { return 2.f * fsig(2.f * x) - 1.f; }

// One block = (layer l, batch tile bi, gate/hidden slice ji).
// W slice lives in VGPRs as MFMA B-fragments for all 1024 steps.
// Cross-block h exchange through IC-coherent (agent-scope, sc1) atomics in d_ws.
template <int KS>
__device__ void lstm_body(int l, int bi, int ji,
    const float* __restrict__ x,
    const float* __restrict__ h0, const float* __restrict__ c0,
    const float* __restrict__ Wih, const float* __restrict__ Whh,
    const float* __restrict__ bih, const float* __restrict__ bhh,
    float* __restrict__ dout,
    u32* pub, u32* cons, u64* ring,
    unsigned short (*A)[LDSK])
{
  const int tid = threadIdx.x;
  const int lane = tid & 63;
  const int w    = tid >> 6;   // wave 0..3
  const int mt   = w & 1;      // m-tile (batch 16-row half)
  const int hh2  = w >> 1;     // hidden 16-col half within slice
  const int q    = lane >> 4;  // quad
  const int lm   = lane & 15;
  const int fin  = (l == 0) ? FF : HH;

  // ---- persistent W fragments (registers), bias, c-state ----
  uint4 wf[4][KS];
  float bias[4];
  float creg[4];
  const int hcol = ji * HS + hh2 * 16 + lm;    // hidden col 0..255 this lane owns
  {
    #pragma unroll
    for (int g = 0; g < 4; ++g) {            // gate = n-tile (i,f,g,o)
      const int row = g * HH + hcol;         // gate row of [Wih|Whh]
      bias[g] = bih[row] + bhh[row];
      #pragma unroll
      for (int ks = 0; ks < KS; ++ks) {
        const int kb = ks * 32 + q * 8;      // B-frag: lane holds W[n=lm][k = kb..kb+7]
        unsigned short uu[8];
        #pragma unroll
        for (int j = 0; j < 8; ++j) {
          const int k = kb + j;
          float v;
          if (k < HH) v = Whh[row * HH + k];                       // h part: K 0..255
          else { const int kk = k - HH; v = (kk < fin) ? Wih[row * fin + kk] : 0.f; } // x part
          uu[j] = f2bf(v);
        }
        wf[g][ks] = make_uint4(
            (u32)uu[0] | ((u32)uu[1] << 16),
            (u32)uu[2] | ((u32)uu[3] << 16),
            (u32)uu[4] | ((u32)uu[5] << 16),
            (u32)uu[6] | ((u32)uu[7] << 16));
      }
    }
    const int bb = bi * BT + mt * 16 + q * 4;
    #pragma unroll
    for (int r = 0; r < 4; ++r)
      creg[r] = c0[((size_t)l * BB + bb + r) * HH + hcol];
  }

  const int gid = l * NB + bi;
  u32* pubown = pub + (size_t)gid * TT;
  u32* publow = pub + (size_t)(gid - NB) * TT;        // valid only for l>0
  u64* ringown = ring + (size_t)gid * DSLOT * (BT * HH / 4);
  u64* ringlow = ring + (size_t)(gid - NB) * DSLOT * (BT * HH / 4);

  #pragma unroll 1
  for (int t = 0; t < TT; ++t) {
    // ---- waits (thread 0 polls IC-coherent flags; others park at barrier) ----
    if (tid == 0) {
      if (l > 0)
        while (__hip_atomic_load(&publow[t], __ATOMIC_RELAXED, __HIP_MEMORY_SCOPE_AGENT) < (u32)NJ)
          __builtin_amdgcn_s_sleep(1);
      if (t > 0)
        while (__hip_atomic_load(&pubown[t - 1], __ATOMIC_RELAXED, __HIP_MEMORY_SCOPE_AGENT) < (u32)NJ)
          __builtin_amdgcn_s_sleep(1);
      if (l < 2 && t >= DSLOT)  // back-pressure: next layer must have consumed step t-DSLOT
        while (__hip_atomic_load(&cons[gid], __ATOMIC_RELAXED, __HIP_MEMORY_SCOPE_AGENT)
               < (u32)(NJ * (t - DSLOT + 1)))
          __builtin_amdgcn_s_sleep(1);
    }
    __syncthreads();

    // ---- stage A rows: [BT][0..255] = h_{t-1}, [BT][256..] = x_t ----
    if (t == 0) {
      const float* hs = h0 + ((size_t)l * BB + bi * BT) * HH;
      #pragma unroll
      for (int i = 0; i < 8; ++i) {
        const int j = i * 256 + tid;
        const int r = j >> 6, cc = (j & 63) * 4;
        const float* p = &hs[r * HH + cc];
        *(u64*)&A[r][cc] = pack4bf(p[0], p[1], p[2], p[3]);
      }
    } else {
      const u64* src = ringown + (size_t)((t - 1) & (DSLOT - 1)) * (BT * HH / 4);
      #pragma unroll
      for (int i = 0; i < 8; ++i) {
        const int j = i * 256 + tid;
        const int r = j >> 6, cc = (j & 63) * 4;
        *(u64*)&A[r][cc] = __hip_atomic_load(&src[j], __ATOMIC_RELAXED, __HIP_MEMORY_SCOPE_AGENT);
      }
    }
    if (l == 0) {
      #pragma unroll
      for (int i = 0; i < 16; ++i) {          // 32 rows x 128 cols (73 data + zero pad)
        const int idx = i * 256 + tid;
        const int r = idx >> 7, cc = idx & 127;
        const float v = (cc < FF) ? x[(size_t)(bi * BT + r) * (TT * FF) + (size_t)t * FF + cc] : 0.f;
        A[r][256 + cc] = f2bf(v);
      }
    } else {
      const u64* src = ringlow + (size_t)(t & (DSLOT - 1)) * (BT * HH / 4);
      #pragma unroll
      for (int i = 0; i < 8; ++i) {
        const int j = i * 256 + tid;
        const int r = j >> 6, cc = (j & 63) * 4;
        *(u64*)&A[r][256 + cc] = __hip_atomic_load(&src[j], __ATOMIC_RELAXED, __HIP_MEMORY_SCOPE_AGENT);
      }
    }
    __syncthreads();   // staging loads drained (vmcnt 0) for whole block
    if (l > 0 && tid == 0)
      __hip_atomic_fetch_add(&cons[gid - NB], 1u, __ATOMIC_RELAXED, __HIP_MEMORY_SCOPE_AGENT);

    // ---- K-loop: z[32 x 128] += A[32 x K] * Wslice^T, W from registers ----
    f32x4 acc0 = {0.f, 0.f, 0.f, 0.f}, acc1 = acc0, acc2 = acc0, acc3 = acc0;
    #pragma unroll
    for (int ks = 0; ks < KS; ++ks) {
      FragU a; a.u = *(const uint4*)&A[mt * 16 + lm][ks * 32 + q * 8];
      FragU b0, b1, b2, b3;
      b0.u = wf[0][ks]; b1.u = wf[1][ks]; b2.u = wf[2][ks]; b3.u = wf[3][ks];
      acc0 = __builtin_amdgcn_mfma_f32_16x16x32_bf16(a.b, b0.b, acc0, 0, 0, 0);
      acc1 = __builtin_amdgcn_mfma_f32_16x16x32_bf16(a.b, b1.b, acc1, 0, 0, 0);
      acc2 = __builtin_amdgcn_mfma_f32_16x16x32_bf16(a.b, b2.b, acc2, 0, 0, 0);
      acc3 = __builtin_amdgcn_mfma_f32_16x16x32_bf16(a.b, b3.b, acc3, 0, 0, 0);
    }

    // ---- gates: i,f,g,o are the 4 accumulators, same lane/reg => no shuffles ----
    float hv[4];
    #pragma unroll
    for (int r = 0; r < 4; ++r) {
      const float zi = acc0[r] + bias[0];
      const float zf = acc1[r] + bias[1];
      const float zg = acc2[r] + bias[2];
      const float zo = acc3[r] + bias[3];
      const float cn = fsig(zf) * creg[r] + fsig(zi) * ftanh(zg);
      creg[r] = cn;
      hv[r] = fsig(zo) * ftanh(cn);
    }

    // ---- publish h slice to ring (pair bf16 -> u32 agent-scope stores) ----
    {
      u32* dst = (u32*)(ringown + (size_t)(t & (DSLOT - 1)) * (BT * HH / 4));
      #pragma unroll
      for (int r = 0; r < 4; ++r) {
        const u32 mb = f2bf(hv[r]);
        const u32 pb = (u32)__shfl_xor((int)mb, 1, 64);
        if (!(lane & 1)) {
          const int brow = mt * 16 + q * 4 + r;
          __hip_atomic_store(&dst[(brow * HH + hcol) >> 1],
                             (mb & 0xffffu) | (pb << 16),
                             __ATOMIC_RELAXED, __HIP_MEMORY_SCOPE_AGENT);
        }
      }
      if (t == TT - 1) {  // final h/c in fp32 straight to d_out
        const int bb = bi * BT + mt * 16 + q * 4;
        #pragma unroll
        for (int r = 0; r < 4; ++r) {
          dout[HFIN_OFF + ((size_t)l * BB + bb + r) * HH + hcol] = hv[r];
          dout[CFIN_OFF + ((size_t)l * BB + bb + r) * HH + hcol] = creg[r];
        }
      }
    }
    __syncthreads();  // compiler emits s_waitcnt vmcnt(0) before s_barrier -> stores acked
    if (tid == 0)
      __hip_atomic_fetch_add(&pubown[t], 1u, __ATOMIC_RELAXED, __HIP_MEMORY_SCOPE_AGENT);
  }
}

__global__ __launch_bounds__(256, 1) void lstm_kernel(
    const float* __restrict__ x, const float* __restrict__ h0, const float* __restrict__ c0,
    const float* __restrict__ Wih0, const float* __restrict__ Whh0, const float* __restrict__ bih0, const float* __restrict__ bhh0,
    const float* __restrict__ Wih1, const float* __restrict__ Whh1, const float* __restrict__ bih1, const float* __restrict__ bhh1,
    const float* __restrict__ Wih2, const float* __restrict__ Whh2, const float* __restrict__ bih2, const float* __restrict__ bhh2,
    float* __restrict__ dout, u32* pub, u32* cons, u64* ring)
{
  __shared__ unsigned short A[BT][LDSK];  // 33,280 B static LDS (single instance for both paths)
  const int l  = blockIdx.x >> 6;
  const int bi = (blockIdx.x >> 3) & 7;
  const int ji = blockIdx.x & 7;
  const float* Wih = (l == 0) ? Wih0 : (l == 1) ? Wih1 : Wih2;
  const float* Whh = (l == 0) ? Whh0 : (l == 1) ? Whh1 : Whh2;
  const float* bih = (l == 0) ? bih0 : (l == 1) ? bih1 : bih2;
  const float* bhh = (l == 0) ? bhh0 : (l == 1) ? bhh1 : bhh2;
  if (l == 0)
    lstm_body<12>(0, bi, ji, x, h0, c0, Wih, Whh, bih, bhh, dout, pub, cons, ring, A); // K=384 (256+73pad128)
  else
    lstm_body<16>(l, bi, ji, x, h0, c0, Wih, Whh, bih, bhh, dout, pub, cons, ring, A); // K=512
}

__global__ void fc_kernel(const float* __restrict__ dout_r, const float* __restrict__ fcw,
                          const float* __restrict__ fcb, float* __restrict__ out)
{
  const int b = blockIdx.x;
  __shared__ float hrow[HH];
  const float* hs = dout_r + HFIN_OFF + ((size_t)2 * BB + b) * HH;  // ys2[T-1] == h_fin[2]
  for (int i = threadIdx.x; i < HH; i += 64) {
    const float v = hs[i];
    hrow[i] = (v > 0.f) ? v : 0.01f * v;  // leaky relu
  }
  __syncthreads();
  if (threadIdx.x < OO) {
    float s = fcb[threadIdx.x];
    #pragma unroll 8
    for (int k = 0; k < HH; ++k) s += hrow[k] * fcw[threadIdx.x * HH + k];
    out[(size_t)b * OO + threadIdx.x] = s;
  }
}

extern "C" void kernel_launch(void* const* d_in, const int* in_sizes, int n_in,
                              void* d_out, int out_size, void* d_ws, size_t ws_size,
                              hipStream_t stream)
{
  (void)in_sizes; (void)n_in; (void)out_size; (void)ws_size;
  const float* x    = (const float*)d_in[0];
  const float* h0   = (const float*)d_in[1];
  const float* c0   = (const float*)d_in[2];
  const float* Wih0 = (const float*)d_in[3];
  const float* Whh0 = (const float*)d_in[4];
  const float* bih0 = (const float*)d_in[5];
  const float* bhh0 = (const float*)d_in[6];
  const float* Wih1 = (const float*)d_in[7];
  const float* Whh1 = (const float*)d_in[8];
  const float* bih1 = (const float*)d_in[9];
  const float* bhh1 = (const float*)d_in[10];
  const float* Wih2 = (const float*)d_in[11];
  const float* Whh2 = (const float*)d_in[12];
  const float* bih2 = (const float*)d_in[13];
  const float* bhh2 = (const float*)d_in[14];
  const float* fcw  = (const float*)d_in[15];
  const float* fcb  = (const float*)d_in[16];
  float* out = (float*)d_out;

  // ws layout: [0,96KB) pub counters [3][8][1024], then cons[3][8]; ring at 128KB (3 MB)
  u32* pub  = (u32*)d_ws;
  u32* cons = pub + 3 * NB * TT;
  u64* ring = (u64*)((char*)d_ws + 131072);

  hipMemsetAsync(d_ws, 0, 131072, stream);  // zero flags (ws is poisoned 0xAA each launch)
  hipLaunchKernelGGL(lstm_kernel, dim3(3 * NB * NJ), dim3(256), 0, stream,
                     x, h0, c0, Wih0, Whh0, bih0, bhh0, Wih1, Whh1, bih1, bhh1,
                     Wih2, Whh2, bih2, bhh2, out, pub, cons, ring);
  hipLaunchKernelGGL(fc_kernel, dim3(BB), dim3(64), 0, stream, out, fcw, fcb, out);
}

// Round 4
// 7056.526 us; speedup vs baseline: 1.2974x; 1.2974x over previous
//
#include <hip/hip_runtime.h>
#include <hip/hip_bf16.h>

typedef __attribute__((ext_vector_type(8))) short bf16x8;
typedef __attribute__((ext_vector_type(4))) float f32x4;
typedef unsigned int u32;
typedef unsigned long long u64;

static constexpr int TT = 1024, BB = 256, HH = 256, FF = 73, OO = 35;
static constexpr int NB = 8;    // batch tiles
static constexpr int NJ = 8;    // gate-slice blocks per tile
static constexpr int BT = 32;   // batch rows per tile
static constexpr int HS = 32;   // hidden cols per slice
static constexpr int DSLOT = 8; // ring depth
static constexpr int LDSK = 520; // padded A row; 520*2B = 1040 = 65*16 -> rows stay 16B-aligned
static constexpr int HFIN_OFF = BB * OO;
static constexpr int CFIN_OFF = HFIN_OFF + 3 * BB * HH;

union FragU { uint4 u; bf16x8 b; };

__device__ __forceinline__ unsigned short f2bf(float f) {
  __hip_bfloat16 h = __float2bfloat16(f);
  union { __hip_bfloat16 h; unsigned short s; } cv; cv.h = h; return cv.s;
}
__device__ __forceinline__ u64 pack4bf(float a, float b, float c, float d) {
  return (u64)f2bf(a) | ((u64)f2bf(b) << 16) | ((u64)f2bf(c) << 32) | ((u64)f2bf(d) << 48);
}
__device__ __forceinline__ float fsig(float x) { return 1.f / (1.f + __expf(-x)); }
__device__ __forceinline__ float ftanh(float x) { return 2.f * fsig(2.f * x) - 1.f; }

// ---- coherent (IC-serviced, sc0 sc1) bursts: loads + drain fused in ONE asm block
// so the waitcnt is provably after all loads and before any use (no tied operands).
__device__ __forceinline__ void stg_coh_b32(void* p, u32 v) {
  asm volatile("global_store_dword %0, %1, off sc0 sc1" :: "v"(p), "v"(v) : "memory");
}
__device__ __forceinline__ void vm_drain() {
  asm volatile("s_waitcnt vmcnt(0)" ::: "memory");
}
__device__ __forceinline__ void poll6(const u32* p0, const u32* p1, const u32* p2,
    uint4& a0, uint4& a1, uint4& b0, uint4& b1, uint4& c0, uint4& c1)
{
  asm volatile(
      "global_load_dwordx4 %0, %6, off sc0 sc1\n\t"
      "global_load_dwordx4 %1, %7, off sc0 sc1\n\t"
      "global_load_dwordx4 %2, %8, off sc0 sc1\n\t"
      "global_load_dwordx4 %3, %9, off sc0 sc1\n\t"
      "global_load_dwordx4 %4, %10, off sc0 sc1\n\t"
      "global_load_dwordx4 %5, %11, off sc0 sc1\n\t"
      "s_waitcnt vmcnt(0)"
      : "=&v"(a0), "=&v"(a1), "=&v"(b0), "=&v"(b1), "=&v"(c0), "=&v"(c1)
      : "v"(p0), "v"(p0 + 4), "v"(p1), "v"(p1 + 4), "v"(p2), "v"(p2 + 4)
      : "memory");
}
__device__ __forceinline__ void ld4_wait(const u32* q0, const u32* q1,
    const u32* q2, const u32* q3,
    uint4& v0, uint4& v1, uint4& v2, uint4& v3)
{
  asm volatile(
      "global_load_dwordx4 %0, %4, off sc0 sc1\n\t"
      "global_load_dwordx4 %1, %5, off sc0 sc1\n\t"
      "global_load_dwordx4 %2, %6, off sc0 sc1\n\t"
      "global_load_dwordx4 %3, %7, off sc0 sc1\n\t"
      "s_waitcnt vmcnt(0)"
      : "=&v"(v0), "=&v"(v1), "=&v"(v2), "=&v"(v3)
      : "v"(q0), "v"(q1), "v"(q2), "v"(q3)
      : "memory");
}
__device__ __forceinline__ void ld8_wait(const u32* q0, const u32* q1,
    const u32* q2, const u32* q3, const u32* q4, const u32* q5,
    const u32* q6, const u32* q7,
    uint4& v0, uint4& v1, uint4& v2, uint4& v3,
    uint4& v4, uint4& v5, uint4& v6, uint4& v7)
{
  asm volatile(
      "global_load_dwordx4 %0, %8, off sc0 sc1\n\t"
      "global_load_dwordx4 %1, %9, off sc0 sc1\n\t"
      "global_load_dwordx4 %2, %10, off sc0 sc1\n\t"
      "global_load_dwordx4 %3, %11, off sc0 sc1\n\t"
      "global_load_dwordx4 %4, %12, off sc0 sc1\n\t"
      "global_load_dwordx4 %5, %13, off sc0 sc1\n\t"
      "global_load_dwordx4 %6, %14, off sc0 sc1\n\t"
      "global_load_dwordx4 %7, %15, off sc0 sc1\n\t"
      "s_waitcnt vmcnt(0)"
      : "=&v"(v0), "=&v"(v1), "=&v"(v2), "=&v"(v3),
        "=&v"(v4), "=&v"(v5), "=&v"(v6), "=&v"(v7)
      : "v"(q0), "v"(q1), "v"(q2), "v"(q3), "v"(q4), "v"(q5), "v"(q6), "v"(q7)
      : "memory");
}
__device__ __forceinline__ bool ge8(uint4 a, uint4 b, u32 need) {
  return a.x >= need && a.y >= need && a.z >= need && a.w >= need &&
         b.x >= need && b.y >= need && b.z >= need && b.w >= need;
}

// One block = (layer l, batch tile bi, gate/hidden slice ji). W slice persistent in
// VGPR/AGPR as MFMA B-fragments. Cross-block h exchange via sc0/sc1 coherent ring +
// per-slice monotonic flag words (no RMW).
template <int KS>
__device__ void lstm_body(int l, int bi, int ji,
    const float* __restrict__ x,
    const float* __restrict__ h0, const float* __restrict__ c0,
    const float* __restrict__ Wih, const float* __restrict__ Whh,
    const float* __restrict__ bih, const float* __restrict__ bhh,
    float* __restrict__ dout,
    u32* flg, u32* cns, u64* ring,
    unsigned short (*A)[LDSK])
{
  const int tid = threadIdx.x;
  const int lane = tid & 63;
  const int w    = tid >> 6;
  const int mt   = w & 1;      // m-tile (16-row batch half)
  const int hh2  = w >> 1;     // 16-col hidden half within slice
  const int q    = lane >> 4;
  const int lm   = lane & 15;
  const int fin  = (l == 0) ? FF : HH;

  uint4 wf[4][KS];
  float bias[4];
  float creg[4];
  const int hcol = ji * HS + hh2 * 16 + lm;
  {
    #pragma unroll
    for (int g = 0; g < 4; ++g) {
      const int row = g * HH + hcol;
      bias[g] = bih[row] + bhh[row];
      #pragma unroll
      for (int ks = 0; ks < KS; ++ks) {
        const int kb = ks * 32 + q * 8;
        unsigned short uu[8];
        #pragma unroll
        for (int j = 0; j < 8; ++j) {
          const int k = kb + j;
          float v;
          if (k < HH) v = Whh[row * HH + k];
          else { const int kk = k - HH; v = (kk < fin) ? Wih[row * fin + kk] : 0.f; }
          uu[j] = f2bf(v);
        }
        wf[g][ks] = make_uint4(
            (u32)uu[0] | ((u32)uu[1] << 16), (u32)uu[2] | ((u32)uu[3] << 16),
            (u32)uu[4] | ((u32)uu[5] << 16), (u32)uu[6] | ((u32)uu[7] << 16));
      }
    }
    const int bb = bi * BT + mt * 16 + q * 4;
    #pragma unroll
    for (int r = 0; r < 4; ++r)
      creg[r] = c0[((size_t)l * BB + bb + r) * HH + hcol];
  }

  const int gid = l * NB + bi;
  u64* ringown = ring + (size_t)gid * DSLOT * (BT * HH / 4);
  u64* ringlow = ring + (size_t)(gid - NB) * DSLOT * (BT * HH / 4);
  const u32* pO = flg + gid * 32;                       // own-group slice flags (8)
  const u32* pL = (l > 0) ? flg + (gid - NB) * 32 : pO; // lower-group flags
  const u32* pC = (l < 2) ? cns + gid * 32 : pO;        // consumer progress slots

  #pragma unroll 1
  for (int t = 0; t < TT; ++t) {
    // ---- issue x loads early (layer 0): overlap HBM latency with the flag wait ----
    float xr0[8], xr1[8];
    if (l == 0) {
      #pragma unroll
      for (int i = 0; i < 8; ++i) {
        const int idx = i * 256 + tid;
        const int r = idx >> 6, c2 = (idx & 63) * 2;
        const float* px = &x[(size_t)(bi * BT + r) * (TT * FF) + (size_t)t * FF + c2];
        xr0[i] = (c2 < FF) ? px[0] : 0.f;
        xr1[i] = (c2 + 1 < FF) ? px[1] : 0.f;
      }
    }

    // ---- wait: own group published t-1; lower group published t; back-pressure ----
    if (tid == 0) {
      const u32 needO = (u32)t;
      const u32 needL = (l > 0) ? (u32)(t + 1) : 0u;
      const u32 needC = (l < 2 && t >= DSLOT) ? (u32)(t - DSLOT + 1) : 0u;
      for (;;) {
        uint4 a0, a1, b0, b1, c0v, c1v;
        poll6(pO, pL, pC, a0, a1, b0, b1, c0v, c1v);
        if (ge8(a0, a1, needO) && ge8(b0, b1, needL) && ge8(c0v, c1v, needC)) break;
        __builtin_amdgcn_s_sleep(1);
      }
    }
    __syncthreads();

    // ---- stage A: [BT][0..255] = h_{t-1}; [BT][256..] = x_t (l==0) / lower h_t ----
    if (t == 0) {
      const float* hs = h0 + ((size_t)l * BB + bi * BT) * HH;
      #pragma unroll
      for (int i = 0; i < 8; ++i) {
        const int j = i * 256 + tid;
        const int r = j >> 6, cc = (j & 63) * 4;
        const float* p = &hs[r * HH + cc];
        *(u64*)&A[r][cc] = pack4bf(p[0], p[1], p[2], p[3]);
      }
      if (l > 0) {  // lower layer's h_0 (slot 0) -> x-part. Poll guaranteed flags>=1.
        const u32* srl = (const u32*)(ringlow + 0);
        uint4 u0, u1, u2, u3;
        ld4_wait(srl + (0 * 256 + tid) * 4, srl + (1 * 256 + tid) * 4,
                 srl + (2 * 256 + tid) * 4, srl + (3 * 256 + tid) * 4,
                 u0, u1, u2, u3);
        #pragma unroll
        for (int i = 0; i < 4; ++i) {
          const int c = i * 256 + tid;
          const int r = c >> 5, col = (c & 31) * 8;
          const uint4 uu = (i == 0) ? u0 : (i == 1) ? u1 : (i == 2) ? u2 : u3;
          *(uint4*)&A[r][256 + col] = uu;
        }
      }
    } else {
      const u32* src = (const u32*)(ringown + (size_t)((t - 1) & (DSLOT - 1)) * (BT * HH / 4));
      uint4 v0, v1, v2, v3;
      if (l > 0) {
        const u32* srl = (const u32*)(ringlow + (size_t)(t & (DSLOT - 1)) * (BT * HH / 4));
        uint4 u0, u1, u2, u3;
        ld8_wait(src + (0 * 256 + tid) * 4, src + (1 * 256 + tid) * 4,
                 src + (2 * 256 + tid) * 4, src + (3 * 256 + tid) * 4,
                 srl + (0 * 256 + tid) * 4, srl + (1 * 256 + tid) * 4,
                 srl + (2 * 256 + tid) * 4, srl + (3 * 256 + tid) * 4,
                 v0, v1, v2, v3, u0, u1, u2, u3);
        #pragma unroll
        for (int i = 0; i < 4; ++i) {
          const int c = i * 256 + tid;
          const int r = c >> 5, col = (c & 31) * 8;
          const uint4 vv = (i == 0) ? v0 : (i == 1) ? v1 : (i == 2) ? v2 : v3;
          const uint4 uu = (i == 0) ? u0 : (i == 1) ? u1 : (i == 2) ? u2 : u3;
          *(uint4*)&A[r][col] = vv;
          *(uint4*)&A[r][256 + col] = uu;
        }
      } else {
        ld4_wait(src + (0 * 256 + tid) * 4, src + (1 * 256 + tid) * 4,
                 src + (2 * 256 + tid) * 4, src + (3 * 256 + tid) * 4,
                 v0, v1, v2, v3);
        #pragma unroll
        for (int i = 0; i < 4; ++i) {
          const int c = i * 256 + tid;
          const int r = c >> 5, col = (c & 31) * 8;
          const uint4 vv = (i == 0) ? v0 : (i == 1) ? v1 : (i == 2) ? v2 : v3;
          *(uint4*)&A[r][col] = vv;
        }
      }
    }
    if (l == 0) {
      #pragma unroll
      for (int i = 0; i < 8; ++i) {
        const int idx = i * 256 + tid;
        const int r = idx >> 6, c2 = (idx & 63) * 2;
        *(u32*)&A[r][256 + c2] = (u32)f2bf(xr0[i]) | ((u32)f2bf(xr1[i]) << 16);
      }
    }
    __syncthreads();
    if (l > 0 && tid == 0)  // back-pressure slot: "I staged lower's step t"
      stg_coh_b32((void*)&cns[(gid - NB) * 32 + ji], (u32)(t + 1));

    // ---- K-loop: z[32 x 128] += A[32 x K] * Wslice^T, W fragments in registers ----
    f32x4 acc0 = {0.f, 0.f, 0.f, 0.f}, acc1 = acc0, acc2 = acc0, acc3 = acc0;
    #pragma unroll
    for (int ks = 0; ks < KS; ++ks) {
      FragU a; a.u = *(const uint4*)&A[mt * 16 + lm][ks * 32 + q * 8];
      FragU b0, b1, b2, b3;
      b0.u = wf[0][ks]; b1.u = wf[1][ks]; b2.u = wf[2][ks]; b3.u = wf[3][ks];
      acc0 = __builtin_amdgcn_mfma_f32_16x16x32_bf16(a.b, b0.b, acc0, 0, 0, 0);
      acc1 = __builtin_amdgcn_mfma_f32_16x16x32_bf16(a.b, b1.b, acc1, 0, 0, 0);
      acc2 = __builtin_amdgcn_mfma_f32_16x16x32_bf16(a.b, b2.b, acc2, 0, 0, 0);
      acc3 = __builtin_amdgcn_mfma_f32_16x16x32_bf16(a.b, b3.b, acc3, 0, 0, 0);
    }

    // ---- gates (i,f,g,o in the 4 accumulators; same lane & reg, no shuffles) ----
    float hv[4];
    #pragma unroll
    for (int r = 0; r < 4; ++r) {
      const float zi = acc0[r] + bias[0];
      const float zf = acc1[r] + bias[1];
      const float zg = acc2[r] + bias[2];
      const float zo = acc3[r] + bias[3];
      const float cn = fsig(zf) * creg[r] + fsig(zi) * ftanh(zg);
      creg[r] = cn;
      hv[r] = fsig(zo) * ftanh(cn);
    }

    // ---- publish h slice (pair lanes -> u32 coherent stores) ----
    {
      u32* dst = (u32*)(ringown + (size_t)(t & (DSLOT - 1)) * (BT * HH / 4));
      #pragma unroll
      for (int r = 0; r < 4; ++r) {
        const u32 mb = f2bf(hv[r]);
        const u32 pb = (u32)__shfl_xor((int)mb, 1, 64);
        if (!(lane & 1)) {
          const int brow = mt * 16 + q * 4 + r;
          stg_coh_b32(&dst[(brow * HH + hcol) >> 1], (mb & 0xffffu) | (pb << 16));
        }
      }
      if (t == TT - 1) {
        const int bb = bi * BT + mt * 16 + q * 4;
        #pragma unroll
        for (int r = 0; r < 4; ++r) {
          dout[HFIN_OFF + ((size_t)l * BB + bb + r) * HH + hcol] = hv[r];
          dout[CFIN_OFF + ((size_t)l * BB + bb + r) * HH + hcol] = creg[r];
        }
      }
    }
    vm_drain();       // asm stores are invisible to the compiler: drain explicitly
    __syncthreads();  // all waves drained -> slice fully visible at IC
    if (tid == 0)
      stg_coh_b32((void*)&flg[gid * 32 + ji], (u32)(t + 1));
  }
}

__global__ __launch_bounds__(256, 1) void lstm_kernel(
    const float* __restrict__ x, const float* __restrict__ h0, const float* __restrict__ c0,
    const float* __restrict__ Wih0, const float* __restrict__ Whh0, const float* __restrict__ bih0, const float* __restrict__ bhh0,
    const float* __restrict__ Wih1, const float* __restrict__ Whh1, const float* __restrict__ bih1, const float* __restrict__ bhh1,
    const float* __restrict__ Wih2, const float* __restrict__ Whh2, const float* __restrict__ bih2, const float* __restrict__ bhh2,
    float* __restrict__ dout, u32* flg, u32* cns, u64* ring)
{
  __shared__ unsigned short A[BT][LDSK];
  const int l  = blockIdx.x >> 6;
  const int bi = (blockIdx.x >> 3) & 7;
  const int ji = blockIdx.x & 7;
  const float* Wih = (l == 0) ? Wih0 : (l == 1) ? Wih1 : Wih2;
  const float* Whh = (l == 0) ? Whh0 : (l == 1) ? Whh1 : Whh2;
  const float* bih = (l == 0) ? bih0 : (l == 1) ? bih1 : bih2;
  const float* bhh = (l == 0) ? bhh0 : (l == 1) ? bhh1 : bhh2;
  if (l == 0)
    lstm_body<12>(0, bi, ji, x, h0, c0, Wih, Whh, bih, bhh, dout, flg, cns, ring, A);
  else
    lstm_body<16>(l, bi, ji, x, h0, c0, Wih, Whh, bih, bhh, dout, flg, cns, ring, A);
}

__global__ void fc_kernel(const float* __restrict__ dout_r, const float* __restrict__ fcw,
                          const float* __restrict__ fcb, float* __restrict__ out)
{
  const int b = blockIdx.x;
  __shared__ float hrow[HH];
  const float* hs = dout_r + HFIN_OFF + ((size_t)2 * BB + b) * HH;  // ys2[T-1] == h_fin[2]
  for (int i = threadIdx.x; i < HH; i += 64) {
    const float v = hs[i];
    hrow[i] = (v > 0.f) ? v : 0.01f * v;
  }
  __syncthreads();
  if (threadIdx.x < OO) {
    float s = fcb[threadIdx.x];
    #pragma unroll 8
    for (int k = 0; k < HH; ++k) s += hrow[k] * fcw[threadIdx.x * HH + k];
    out[(size_t)b * OO + threadIdx.x] = s;
  }
}

extern "C" void kernel_launch(void* const* d_in, const int* in_sizes, int n_in,
                              void* d_out, int out_size, void* d_ws, size_t ws_size,
                              hipStream_t stream)
{
  (void)in_sizes; (void)n_in; (void)out_size; (void)ws_size;
  const float* x    = (const float*)d_in[0];
  const float* h0   = (const float*)d_in[1];
  const float* c0   = (const float*)d_in[2];
  const float* Wih0 = (const float*)d_in[3];
  const float* Whh0 = (const float*)d_in[4];
  const float* bih0 = (const float*)d_in[5];
  const float* bhh0 = (const float*)d_in[6];
  const float* Wih1 = (const float*)d_in[7];
  const float* Whh1 = (const float*)d_in[8];
  const float* bih1 = (const float*)d_in[9];
  const float* bhh1 = (const float*)d_in[10];
  const float* Wih2 = (const float*)d_in[11];
  const float* Whh2 = (const float*)d_in[12];
  const float* bih2 = (const float*)d_in[13];
  const float* bhh2 = (const float*)d_in[14];
  const float* fcw  = (const float*)d_in[15];
  const float* fcb  = (const float*)d_in[16];
  float* out = (float*)d_out;

  // ws layout: [0,3KB) flg[24][32], [3KB,6KB) cns[24][32], ring at 8KB (3 MB)
  u32* flg  = (u32*)d_ws;
  u32* cns  = flg + 24 * 32;
  u64* ring = (u64*)((char*)d_ws + 8192);

  (void)hipMemsetAsync(d_ws, 0, 8192, stream);  // zero flag region (ws is 0xAA-poisoned)
  hipLaunchKernelGGL(lstm_kernel, dim3(3 * NB * NJ), dim3(256), 0, stream,
                     x, h0, c0, Wih0, Whh0, bih0, bhh0, Wih1, Whh1, bih1, bhh1,
                     Wih2, Whh2, bih2, bhh2, out, flg, cns, ring);
  hipLaunchKernelGGL(fc_kernel, dim3(BB), dim3(64), 0, stream, out, fcw, fcb, out);
}